// Round 1
// baseline (1376.597 us; speedup 1.0000x reference)
//
#include <hip/hip_runtime.h>
#include <hip/hip_bf16.h>

typedef __bf16 bf16x8 __attribute__((ext_vector_type(8)));
typedef float  f32x4  __attribute__((ext_vector_type(4)));

#define NPAIRS 640000
#define NATOMS 20000
#define RDIM   128
#define NTILES (NPAIRS / 64)
#define WT_LD  136   // 128 + 8 bf16 pad -> row stride 272B, balances ds_read_b128 slots

__device__ __forceinline__ float tanh_fast(float x) {
  x = fminf(10.f, fmaxf(-10.f, x));
  float e = __expf(2.f * x);
  return __fdividef(e - 1.f, e + 1.f);
}

// K1: fused  i1g = tanh(i1@W_ii + b) (bf16 MFMA)  +  atomic scatter of
//     (p3[j,x,:] + d3[p,x]) * i1g[p,:]  into accb[i,x,:]
// block = 256 (4 waves), each block-iteration = 64 pairs (wave w: rows 16w..16w+15)
__global__ __launch_bounds__(256, 2) void k1_gemm_scatter(
    const int* __restrict__ ind, const float* __restrict__ p3,
    const float* __restrict__ i1, const float* __restrict__ d3,
    const float* __restrict__ Wii, const float* __restrict__ bii,
    float* __restrict__ accb)
{
  __shared__ __bf16 Wt[RDIM * WT_LD];   // W_ii transposed: Wt[r][k], bf16, padded
  __shared__ float  bs[RDIM];

  const int tid = threadIdx.x;
  for (int idx = tid; idx < RDIM * RDIM; idx += 256) {
    int k = idx >> 7, r = idx & 127;           // W_ii[k][r], coalesced read
    Wt[r * WT_LD + k] = (__bf16)Wii[idx];
  }
  if (tid < RDIM) bs[tid] = bii[tid];
  __syncthreads();

  const int w  = tid >> 6;      // wave 0..3
  const int l  = tid & 63;      // lane
  const int lg = l >> 4;        // k-group 0..3
  const int lm = l & 15;        // row (A) / col (B) within 16

  for (int tile = blockIdx.x; tile < NTILES; tile += gridDim.x) {
    const int pbase = tile * 64 + 16 * w;

    f32x4 acc[8];
    #pragma unroll
    for (int n = 0; n < 8; ++n) acc[n] = (f32x4){0.f, 0.f, 0.f, 0.f};

    const float* arow = i1 + (size_t)(pbase + lm) * RDIM;
    #pragma unroll
    for (int kk = 0; kk < 4; ++kk) {
      const int kb = kk * 32 + lg * 8;
      float4 a0 = *(const float4*)(arow + kb);
      float4 a1 = *(const float4*)(arow + kb + 4);
      bf16x8 av;
      av[0] = (__bf16)a0.x; av[1] = (__bf16)a0.y; av[2] = (__bf16)a0.z; av[3] = (__bf16)a0.w;
      av[4] = (__bf16)a1.x; av[5] = (__bf16)a1.y; av[6] = (__bf16)a1.z; av[7] = (__bf16)a1.w;
      #pragma unroll
      for (int n = 0; n < 8; ++n) {
        bf16x8 bv = *(const bf16x8*)&Wt[(n * 16 + lm) * WT_LD + kb];
        acc[n] = __builtin_amdgcn_mfma_f32_16x16x32_bf16(av, bv, acc[n], 0, 0, 0);
      }
    }

    // epilogue: +bias, tanh, scatter with fp32 atomics
    #pragma unroll
    for (int j = 0; j < 4; ++j) {
      const int p  = pbase + lg * 4 + j;        // D row = 4*(l>>4)+reg  (HW-verified)
      const int ia = ind[2 * p], ja = ind[2 * p + 1];
      const float dx0 = d3[3 * p], dx1 = d3[3 * p + 1], dx2 = d3[3 * p + 2];
      const float* prow = p3   + (size_t)ja * 384;
      float*       orow = accb + (size_t)ia * 384;
      #pragma unroll
      for (int n = 0; n < 8; ++n) {
        const int c = n * 16 + lm;              // D col = lane&15 (+16 per tile)
        const float t = tanh_fast(acc[n][j] + bs[c]);
        atomicAdd(orow + c,        (prow[c]       + dx0) * t);
        atomicAdd(orow + c + 128,  (prow[c + 128] + dx1) * t);
        atomicAdd(orow + c + 256,  (prow[c + 256] + dx2) * t);
      }
    }
  }
}

// K2: p3_new = acc @ W_pp (in-place over acc region of d_out) + dotted = sum_x p3_new^2
// block = 256: two atoms per iteration (sub = tid>>7), thread r owns output col r
__global__ __launch_bounds__(256, 2) void k2_out(
    const float* __restrict__ Wpp, float* __restrict__ out)
{
  __shared__ float Ws[RDIM * RDIM];
  __shared__ float arow[2][384];

  const int tid = threadIdx.x;
  for (int idx = tid; idx < RDIM * RDIM; idx += 256) Ws[idx] = Wpp[idx];

  const int sub = tid >> 7, r = tid & 127;
  float* dot = out + (size_t)NATOMS * 384;

  for (int a0 = blockIdx.x * 2; a0 < NATOMS; a0 += gridDim.x * 2) {
    const int a = a0 + sub;
    __syncthreads();  // Ws ready (iter 0); prev iter's arow reads done
    for (int idx = r; idx < 384; idx += 128)
      arow[sub][idx] = out[(size_t)a * 384 + idx];
    __syncthreads();

    float o0 = 0.f, o1 = 0.f, o2 = 0.f;
    #pragma unroll 8
    for (int k = 0; k < RDIM; ++k) {
      const float wv = Ws[k * RDIM + r];        // lanes->consecutive banks, conflict-free
      o0 = fmaf(arow[sub][k],       wv, o0);    // broadcast
      o1 = fmaf(arow[sub][128 + k], wv, o1);
      o2 = fmaf(arow[sub][256 + k], wv, o2);
    }
    out[(size_t)a * 384 + r]       = o0;        // safe: acc row staged in LDS
    out[(size_t)a * 384 + 128 + r] = o1;
    out[(size_t)a * 384 + 256 + r] = o2;
    dot[(size_t)a * 128 + r] = o0 * o0 + o1 * o1 + o2 * o2;
  }
}

extern "C" void kernel_launch(void* const* d_in, const int* in_sizes, int n_in,
                              void* d_out, int out_size, void* d_ws, size_t ws_size,
                              hipStream_t stream) {
  const int*   ind = (const int*)d_in[0];
  const float* p3  = (const float*)d_in[1];
  const float* i1  = (const float*)d_in[2];
  const float* d3  = (const float*)d_in[3];
  const float* Wii = (const float*)d_in[4];
  const float* bii = (const float*)d_in[5];
  const float* Wpp = (const float*)d_in[6];
  float* out = (float*)d_out;

  // zero the segment-sum accumulator region (= p3_new region of d_out)
  hipMemsetAsync(d_out, 0, (size_t)NATOMS * 3 * RDIM * sizeof(float), stream);

  k1_gemm_scatter<<<2560, 256, 0, stream>>>(ind, p3, i1, d3, Wii, bii, out);
  k2_out<<<1280, 256, 0, stream>>>(Wpp, out);
}